// Round 1
// 782.612 us; speedup vs baseline: 1.0055x; 1.0055x over previous
//
#include <hip/hip_runtime.h>

#define BATCH 16384
#define NEG 20
#define DIM 128
#define NSCORE (NEG + 1)
#define WPB 4                 // waves (batch elements) per block
#define GRID (BATCH / WPB)    // 4096 blocks

// Each wave handles one batch element b:
//   - lane i loads elements [2i, 2i+1] of each embedding row (512B coalesced/row)
//   - 21 dot-product partials butterfly-reduced across the wave
//   - ONE transcendental chain per wave: lane k computes loss for score k
//   - block partial written with a plain store (no atomics, no zero-init kernel)
__global__ __launch_bounds__(256) void i2v_main(
    const int* __restrict__ center,
    const int* __restrict__ pos,
    const int* __restrict__ neg,
    const float* __restrict__ W_in,
    const float* __restrict__ W_out,
    float* __restrict__ partial)
{
    const int wave = threadIdx.x >> 6;         // 0..3
    const int lane = threadIdx.x & 63;
    const int b = blockIdx.x * WPB + wave;

    // center embedding: one 512B coalesced read per wave
    const int c = center[b];
    const float2 ce = ((const float2*)(W_in + (size_t)c * DIM))[lane];

    float scores[NSCORE];
#pragma unroll
    for (int k = 0; k < NSCORE; ++k) {
        const int idx = (k == 0) ? pos[b] : neg[b * NEG + (k - 1)];
        const float2 w = ((const float2*)(W_out + (size_t)idx * DIM))[lane];
        scores[k] = ce.x * w.x + ce.y * w.y;
    }

    // batched butterfly: every lane ends with all 21 fully-reduced scores,
    // bit-identical across lanes (same add-tree shape on every lane)
#pragma unroll
    for (int off = 1; off < 64; off <<= 1) {
#pragma unroll
        for (int k = 0; k < NSCORE; ++k)
            scores[k] += __shfl_xor(scores[k], off, 64);
    }

    // lane k picks score k via a STATIC select chain (compile-time indices only;
    // runtime-indexed register arrays would spill to scratch)
    float s = scores[0];
#pragma unroll
    for (int k = 1; k < NSCORE; ++k)
        s = (lane == k) ? scores[k] : s;

    // one exp/log chain per wave instead of 21 redundant ones.
    // pos (k==0):  -log(sigmoid(+s) + eps)
    // neg (k>=1):  -log(sigmoid(-s) + eps)
    float loss = 0.0f;
    if (lane < NSCORE) {
        const float x = (lane == 0) ? s : -s;
        const float p = 1.0f / (1.0f + expf(-x));   // same f32 path as before
        loss = -logf(p + 1e-10f);
    }

    // sum the 21 per-lane losses across the wave (lanes >= 21 contribute 0)
#pragma unroll
    for (int off = 1; off < 64; off <<= 1)
        loss += __shfl_xor(loss, off, 64);

    __shared__ float ls[WPB];
    if (lane == 0) ls[wave] = loss;
    __syncthreads();
    if (threadIdx.x == 0)
        partial[blockIdx.x] = ls[0] + ls[1] + ls[2] + ls[3];  // plain store: no init needed
}

__global__ __launch_bounds__(256) void i2v_finalize(
    const float* __restrict__ partial, float* __restrict__ out)
{
    float s = 0.0f;
    for (int i = threadIdx.x; i < GRID; i += 256)   // coalesced, 16 per thread
        s += partial[i];
#pragma unroll
    for (int off = 1; off < 64; off <<= 1)
        s += __shfl_xor(s, off, 64);

    __shared__ float ls[4];
    if ((threadIdx.x & 63) == 0) ls[threadIdx.x >> 6] = s;
    __syncthreads();
    if (threadIdx.x == 0)
        out[0] = (ls[0] + ls[1] + ls[2] + ls[3]) * (1.0f / (float)BATCH);
}

extern "C" void kernel_launch(void* const* d_in, const int* in_sizes, int n_in,
                              void* d_out, int out_size, void* d_ws, size_t ws_size,
                              hipStream_t stream)
{
    const int*   center = (const int*)d_in[0];
    const int*   pos    = (const int*)d_in[1];
    const int*   neg    = (const int*)d_in[2];
    const float* W_in   = (const float*)d_in[3];
    const float* W_out  = (const float*)d_in[4];
    float* out = (float*)d_out;
    float* ws  = (float*)d_ws;   // 4096 floats of per-block partials (fully overwritten)

    i2v_main<<<GRID, 256, 0, stream>>>(center, pos, neg, W_in, W_out, ws);
    i2v_finalize<<<1, 256, 0, stream>>>(ws, out);
}